// Round 6
// baseline (260.040 us; speedup 1.0000x reference)
//
#include <hip/hip_runtime.h>
#include <math.h>

#define Bv 2
#define Cc 4
#define Dd 64
#define Hh 192
#define Ww 192
#define HW (Hh*Ww)           // 36864
#define NSLICE (Bv*Dd)       // 128
#define NVOX ((size_t)NSLICE*HW)  // 4718592
#define DHW (Dd*HW)          // 2359296
#define LPB 4608             // pixels per prep block (24 rows)

typedef unsigned long long u64;

// masks layout: [slice][c-1][row][4] u64 (words 0..2 used, stride padded to 32B)
#define MROWSTRIDE 4
#define MASKU64 ((size_t)NSLICE*3*Hh*MROWSTRIDE)

// wave-aggregated LDS list push: 1 LDS atomic per wave per call
__device__ __forceinline__ void push32(unsigned* list, unsigned* cnt,
    bool want, unsigned val) {
  u64 mask = __ballot(want);
  if (mask == 0) return;
  int lane = threadIdx.x & 63;
  int total = __popcll(mask);
  int leader = __ffsll((long long)mask) - 1;
  unsigned b = 0;
  if (lane == leader) b = atomicAdd(cnt, (unsigned)total);
  b = __shfl(b, leader);
  if (want) {
    int off = __popcll(mask & ((1ull << lane) - 1));
    list[b + off] = val;
  }
}

// ---------------- Kernel A: focal + packed tv/pred + masks + flags + worklist --
// grid: NSLICE*8 blocks of 256; block covers 24 rows (4608 px) of one slice.
__global__ __launch_bounds__(256) void prep_kernel(const float* __restrict__ inp,
    const int* __restrict__ tgt, unsigned char* __restrict__ tp,
    float* __restrict__ focal, u64* __restrict__ masks,
    unsigned int* __restrict__ flags, unsigned int* __restrict__ gcnt,
    unsigned int* __restrict__ glist) {
  __shared__ unsigned slist[LPB];
  __shared__ unsigned scnt, gbase, sb;
  int part  = blockIdx.x & 7;
  int slice = blockIdx.x >> 3;
  int b = slice >> 6, d = slice & 63;
  int wave = threadIdx.x >> 6, lane = threadIdx.x & 63;
  const float* c0 = inp + ((size_t)(b*Cc)*Dd + d)*HW;
  const float* c1p = c0 + DHW;
  const float* c2p = c0 + 2*DHW;
  const float* c3p = c0 + 3*DHW;
  const int*   tb = tgt + (size_t)slice*HW;
  unsigned int lbits = 0;
  if (threadIdx.x == 0) { scnt = 0u; sb = 0u; }
  __syncthreads();

  for (int it = 0; it < 6; ++it) {
    int lr  = wave*6 + it;            // local row 0..23
    int row = part*24 + lr;
    int idx = row*Ww + lane*4;
    float4 x0, x1, x2, x3;
    int4 tv4 = make_int4(0,0,0,0), up4 = make_int4(-1,-1,-1,-1), dn4 = make_int4(-1,-1,-1,-1);
    if (lane < 48) {
      x0 = *(const float4*)(c0 + idx);
      x1 = *(const float4*)(c1p + idx);
      x2 = *(const float4*)(c2p + idx);
      x3 = *(const float4*)(c3p + idx);
      tv4 = *(const int4*)(tb + idx);
      if (row > 0)    up4 = *(const int4*)(tb + idx - Ww);
      if (row < Hh-1) dn4 = *(const int4*)(tb + idx + Ww);
    }
    int lf = __shfl(tv4.w, (lane-1)&63);
    int rt = __shfl(tv4.x, (lane+1)&63);
    unsigned nib1 = 0, nib2 = 0, nib3 = 0;
    if (lane < 48) {
      int tvs[4] = {tv4.x, tv4.y, tv4.z, tv4.w};
      int ups[4] = {up4.x, up4.y, up4.z, up4.w};
      int dns[4] = {dn4.x, dn4.y, dn4.z, dn4.w};
      int lfs[4] = {lf, tv4.x, tv4.y, tv4.z};
      int rts[4] = {tv4.y, tv4.z, tv4.w, rt};
      float a0[4] = {x0.x, x0.y, x0.z, x0.w};
      float a1[4] = {x1.x, x1.y, x1.z, x1.w};
      float a2[4] = {x2.x, x2.y, x2.z, x2.w};
      float a3[4] = {x3.x, x3.y, x3.z, x3.w};
      float4 fout;
      float* fo = (float*)&fout;
      unsigned pk4 = 0;
      #pragma unroll
      for (int k = 0; k < 4; ++k) {
        float xa = a0[k], xb = a1[k], xc = a2[k], xd = a3[k];
        int p = 0; float bst = xa;
        if (xb > bst) { bst = xb; p = 1; }
        if (xc > bst) { bst = xc; p = 2; }
        if (xd > bst) { bst = xd; p = 3; }
        int tv = tvs[k];
        float m = fmaxf(fmaxf(xa, xb), fmaxf(xc, xd));
        float e = expf(xa-m) + expf(xb-m) + expf(xc-m) + expf(xd-m);
        float xt = (tv==0) ? xa : (tv==1) ? xb : (tv==2) ? xc : xd;
        float logpt = xt - m - logf(e);
        float pt = expf(logpt);
        float om = 1.0f - pt;
        fo[k] = -(om*om)*logpt;
        pk4 |= (unsigned)(tv | (p << 4)) << (8*k);
        if (tv != 0) {
          lbits |= 1u << (tv-1);
          int col = lane*4 + k;
          bool interior = (row > 0) && (row < Hh-1) && (col > 0) && (col < Ww-1)
              && (ups[k]==tv) && (dns[k]==tv) && (lfs[k]==tv) && (rts[k]==tv);
          if (!interior) {
            if      (tv == 1) nib1 |= 1u << k;
            else if (tv == 2) nib2 |= 1u << k;
            else              nib3 |= 1u << k;
          }
        }
        // worklist item: one per error voxel, both classes packed
        bool diff = (tv != p);
        int cA, cB;
        if (tv && p) { cA = tv; cB = p; } else { cA = tv | p; cB = 0; }
        int lidx = lr*Ww + lane*4 + k;
        unsigned val = (unsigned)((size_t)slice*HW + part*LPB + lidx)
                     | ((unsigned)cA << 23) | ((unsigned)cB << 25);
        push32(slist, &scnt, diff, val);
      }
      *(float4*)(focal + (size_t)slice*HW + idx) = fout;
      *(unsigned*)(tp + (size_t)slice*HW + idx) = pk4;
    } else {
      // lanes 48..63 participate in the 4 ballots with want=false
      #pragma unroll
      for (int k = 0; k < 4; ++k) push32(slist, &scnt, false, 0u);
    }
    u64 m1 = (u64)nib1 << ((lane & 15)*4);
    u64 m2 = (u64)nib2 << ((lane & 15)*4);
    u64 m3 = (u64)nib3 << ((lane & 15)*4);
    #pragma unroll
    for (int off = 1; off < 16; off <<= 1) {
      m1 |= __shfl_xor(m1, off);
      m2 |= __shfl_xor(m2, off);
      m3 |= __shfl_xor(m3, off);
    }
    if (lane < 48 && (lane & 15) == 0) {
      int word = lane >> 4;
      size_t base = ((size_t)slice*3*Hh + row)*MROWSTRIDE + word;
      masks[base]                    = m1;
      masks[base + Hh*MROWSTRIDE]    = m2;
      masks[base + 2*Hh*MROWSTRIDE]  = m3;
    }
  }
  if (lbits) atomicOr(&sb, lbits);
  __syncthreads();
  unsigned n = scnt;
  if (threadIdx.x == 0) {
    if (sb) atomicOr(&flags[slice], sb);
    if (n) gbase = atomicAdd(gcnt, n);
  }
  __syncthreads();
  unsigned gb = gbase;
  for (unsigned i = threadIdx.x; i < n; i += 256) glist[gb + i] = slist[i];
}

// nearest set bit distance from column j in a 192-bit row mask; 1<<20 if empty
__device__ __forceinline__ int nearest_bit_dist(u64 m0, u64 m1, u64 m2, int j) {
  int dr = 1<<20, dl = 1<<20;
  u64 r0, r1, r2;
  if (j >= 128)      { r0 = 0;  r1 = 0;  r2 = m2 & (~0ull << (j-128)); }
  else if (j >= 64)  { r0 = 0;  r1 = m1 & (~0ull << (j-64)); r2 = m2; }
  else               { r0 = m0 & (~0ull << j); r1 = m1; r2 = m2; }
  if      (r0) dr = (__ffsll((unsigned long long)r0) - 1) - j;
  else if (r1) dr = (__ffsll((unsigned long long)r1) + 63) - j;
  else if (r2) dr = (__ffsll((unsigned long long)r2) + 127) - j;
  u64 l0, l1, l2;
  if (j < 64)        { l0 = (j==63) ? m0 : (m0 & ((1ull<<(j+1))-1)); l1 = 0; l2 = 0; }
  else if (j < 128)  { l0 = m0; l1 = (j==127) ? m1 : (m1 & ((1ull<<(j-63))-1)); l2 = 0; }
  else               { l0 = m0; l1 = m1; l2 = (j==191) ? m2 : (m2 & ((1ull<<(j-127))-1)); }
  if      (l2) dl = j - (191 - __clzll((long long)l2));
  else if (l1) dl = j - (127 - __clzll((long long)l1));
  else if (l0) dl = j - (63  - __clzll((long long)l0));
  return dl < dr ? dl : dr;
}

// ---------------- Kernel B: grid-stride exact EDT over global worklist -------
__global__ __launch_bounds__(256) void edt_kernel(const unsigned* __restrict__ glist,
    const unsigned* __restrict__ gcnt, const u64* __restrict__ masks,
    const unsigned int* __restrict__ flags, float* __restrict__ wmap) {
  unsigned n = *gcnt;
  unsigned stride = gridDim.x*256;
  for (unsigned k = blockIdx.x*256 + threadIdx.x; k < n; k += stride) {
    unsigned item = glist[k];
    unsigned v = item & 0x7FFFFFu;
    int slice = v / HW;
    int idx = v - slice*HW;
    int i = idx / Ww, j = idx - i*Ww;
    unsigned fl = flags[slice];
    const u64* msl = masks + (size_t)slice*3*Hh*MROWSTRIDE;
    int cA = (item >> 23) & 3, cB = (item >> 25) & 3;
    float sum = 0.0f;
    #pragma unroll
    for (int t = 0; t < 2; ++t) {
      int c = t ? cB : cA;
      if (c && ((fl >> (c-1)) & 1u)) {
        const u64* M = msl + (size_t)(c-1)*Hh*MROWSTRIDE;
        int best = 1 << 30;
        for (int dr = 0; dr < Hh; ++dr) {
          int dr2 = dr*dr;
          if (dr2 >= best) break;
          int up = i - dr;
          if (up >= 0) {
            const u64* R = M + up*MROWSTRIDE;
            int dc = nearest_bit_dist(R[0], R[1], R[2], j);
            if (dc < (1<<20)) { int cand = dr2 + dc*dc; if (cand < best) best = cand; }
          }
          int dn = i + dr;
          if (dr && dn < Hh) {
            const u64* R = M + dn*MROWSTRIDE;
            int dc = nearest_bit_dist(R[0], R[1], R[2], j);
            if (dc < (1<<20)) { int cand = dr2 + dc*dc; if (cand < best) best = cand; }
          }
        }
        sum += (best == (1 << 30)) ? 1.0e6f : sqrtf((float)best);
      }
    }
    if (sum != 0.0f) atomicAdd(&wmap[v], sum);
  }
}

// ---------------- Kernel C: per-slice min/max (+empty-slice penalty) ---------
__global__ __launch_bounds__(256) void minmax_kernel(float* __restrict__ wmap,
    const unsigned char* __restrict__ tp, const unsigned int* __restrict__ flags,
    unsigned int* __restrict__ mnb, unsigned int* __restrict__ mxb) {
  int part  = blockIdx.x % 9;
  int slice = blockIdx.x / 9;
  bool empty = ((flags[slice] & 7u) == 0u);
  float lmn = 1.0e30f, lmx = 0.0f;
  for (int it = 0; it < 4; ++it) {
    int idx = part*4096 + it*1024 + threadIdx.x*4;
    float4 w = *(float4*)(wmap + (size_t)slice*HW + idx);
    if (empty) {   // slice-uniform branch
      unsigned pk = *(const unsigned*)(tp + (size_t)slice*HW + idx);
      float* wp = (float*)&w;
      #pragma unroll
      for (int k = 0; k < 4; ++k)
        if ((pk >> (8*k)) & 0xF0u) wp[k] += 10.0f;
      *(float4*)(wmap + (size_t)slice*HW + idx) = w;
    }
    lmn = fminf(lmn, fminf(fminf(w.x, w.y), fminf(w.z, w.w)));
    lmx = fmaxf(lmx, fmaxf(fmaxf(w.x, w.y), fmaxf(w.z, w.w)));
  }
  for (int off = 32; off; off >>= 1) {
    lmn = fminf(lmn, __shfl_xor(lmn, off));
    lmx = fmaxf(lmx, __shfl_xor(lmx, off));
  }
  __shared__ float smn[4], smx[4];
  int wid = threadIdx.x >> 6;
  if ((threadIdx.x & 63) == 0) { smn[wid] = lmn; smx[wid] = lmx; }
  __syncthreads();
  if (threadIdx.x == 0) {
    lmn = fminf(fminf(smn[0], smn[1]), fminf(smn[2], smn[3]));
    lmx = fmaxf(fmaxf(smx[0], smx[1]), fmaxf(smx[2], smx[3]));
    atomicMin(&mnb[slice], __float_as_uint(lmn));
    atomicMax(&mxb[slice], __float_as_uint(lmx));
  }
}

// ---------------- Kernel D: sum focal * exp(normalized wmap) -----------------
__global__ __launch_bounds__(256) void loss_kernel(const float* __restrict__ focal,
    const float* __restrict__ wmap, const unsigned int* __restrict__ mnb,
    const unsigned int* __restrict__ mxb, float* __restrict__ out) {
  int part  = blockIdx.x % 9;
  int slice = blockIdx.x / 9;
  float mn = __uint_as_float(mnb[slice]);
  float mx = __uint_as_float(mxb[slice]);
  float inv = 1.0f/(mx - mn + 1e-6f);
  float acc = 0.0f;
  for (int it = 0; it < 4; ++it) {
    int idx = part*4096 + it*1024 + threadIdx.x*4;
    float4 f = *(const float4*)(focal + (size_t)slice*HW + idx);
    float4 w = *(const float4*)(wmap + (size_t)slice*HW + idx);
    acc += f.x * expf((w.x-mn)*inv);
    acc += f.y * expf((w.y-mn)*inv);
    acc += f.z * expf((w.z-mn)*inv);
    acc += f.w * expf((w.w-mn)*inv);
  }
  for (int off = 32; off; off >>= 1) acc += __shfl_xor(acc, off);
  __shared__ float sa[4];
  int wid = threadIdx.x >> 6;
  if ((threadIdx.x & 63) == 0) sa[wid] = acc;
  __syncthreads();
  if (threadIdx.x == 0) atomicAdd(out, sa[0]+sa[1]+sa[2]+sa[3]);
}

extern "C" void kernel_launch(void* const* d_in, const int* in_sizes, int n_in,
                              void* d_out, int out_size, void* d_ws, size_t ws_size,
                              hipStream_t stream) {
  const float* inp = (const float*)d_in[0];
  const int*   tgt = (const int*)d_in[1];
  char* ws = (char*)d_ws;
  unsigned char* tp    = (unsigned char*)ws;                 // NVOX
  float*         focal = (float*)(ws + NVOX);                // 4*NVOX
  float*         wmap  = (float*)(ws + 5*NVOX);              // 4*NVOX
  u64*           masks = (u64*)(ws + 9*NVOX);                // MASKU64*8
  unsigned int*  flags = (unsigned int*)(ws + 9*NVOX + MASKU64*8);
  unsigned int*  mxb   = flags + NSLICE;
  unsigned int*  gcnt  = mxb + NSLICE;                       // 1 u32 (zeroed with flags/mxb)
  unsigned int*  mnb   = gcnt + 1;                           // NSLICE u32 (0xFF memset)
  unsigned int*  glist = mnb + NSLICE;                       // up to NVOX u32

  hipMemsetAsync(flags, 0, (2*NSLICE+1)*sizeof(unsigned int), stream); // flags+mxb+gcnt
  hipMemsetAsync(mnb, 0xFF, NSLICE*sizeof(unsigned int), stream);
  hipMemsetAsync(wmap, 0, NVOX*sizeof(float), stream);
  hipMemsetAsync(d_out, 0, sizeof(float), stream);

  prep_kernel<<<NSLICE*8, 256, 0, stream>>>(inp, tgt, tp, focal, masks, flags, gcnt, glist);
  edt_kernel<<<2048, 256, 0, stream>>>(glist, gcnt, masks, flags, wmap);
  minmax_kernel<<<NSLICE*9, 256, 0, stream>>>(wmap, tp, flags, mnb, mxb);
  loss_kernel<<<NSLICE*9, 256, 0, stream>>>(focal, wmap, mnb, mxb, (float*)d_out);
}

// Round 7
// 219.689 us; speedup vs baseline: 1.1837x; 1.1837x over previous
//
#include <hip/hip_runtime.h>
#include <math.h>

#define Bv 2
#define Cc 4
#define Dd 64
#define Hh 192
#define Ww 192
#define HW (Hh*Ww)           // 36864
#define NSLICE (Bv*Dd)       // 128
#define NVOX ((size_t)NSLICE*HW)  // 4718592
#define DHW (Dd*HW)          // 2359296

typedef unsigned long long u64;

// global masks layout: [slice][c-1][row][4] u64 (words 0..2 used)
#define MROWSTRIDE 4
#define MASKU64 ((size_t)NSLICE*3*Hh*MROWSTRIDE)

// edt tiling
#define TROWS 4
#define TPX (TROWS*Ww)            // 768 px per edt block
#define MARGIN 12                 // staged ring radius
#define SROWS (TROWS + 2*MARGIN)  // 28 staged rows
#define SSTRIDE 5                 // u64 per staged row (40B -> bank spread)
#define NTILE (Hh/TROWS)          // 48 tiles per slice

// ---------------- Kernel A: focal + packed tv/pred + seed masks + flags8 -----
// grid: NSLICE*8 blocks of 256; block covers 24 rows of one slice.
__global__ __launch_bounds__(256) void prep_kernel(const float* __restrict__ inp,
    const int* __restrict__ tgt, unsigned char* __restrict__ tp,
    float* __restrict__ focal, u64* __restrict__ masks,
    unsigned int* __restrict__ flags8) {
  int part  = blockIdx.x & 7;
  int slice = blockIdx.x >> 3;
  int b = slice >> 6, d = slice & 63;
  int wave = threadIdx.x >> 6, lane = threadIdx.x & 63;
  const float* c0 = inp + ((size_t)(b*Cc)*Dd + d)*HW;
  const float* c1p = c0 + DHW;
  const float* c2p = c0 + 2*DHW;
  const float* c3p = c0 + 3*DHW;
  const int*   tb = tgt + (size_t)slice*HW;
  unsigned int lbits = 0;
  __shared__ unsigned int sb;
  if (threadIdx.x == 0) sb = 0u;
  __syncthreads();

  for (int it = 0; it < 6; ++it) {
    int row = part*24 + wave*6 + it;
    int idx = row*Ww + lane*4;
    float4 x0, x1, x2, x3;
    int4 tv4 = make_int4(0,0,0,0), up4 = make_int4(-1,-1,-1,-1), dn4 = make_int4(-1,-1,-1,-1);
    if (lane < 48) {
      x0 = *(const float4*)(c0 + idx);
      x1 = *(const float4*)(c1p + idx);
      x2 = *(const float4*)(c2p + idx);
      x3 = *(const float4*)(c3p + idx);
      tv4 = *(const int4*)(tb + idx);
      if (row > 0)    up4 = *(const int4*)(tb + idx - Ww);
      if (row < Hh-1) dn4 = *(const int4*)(tb + idx + Ww);
    }
    int lf = __shfl(tv4.w, (lane-1)&63);
    int rt = __shfl(tv4.x, (lane+1)&63);
    unsigned nib1 = 0, nib2 = 0, nib3 = 0;
    if (lane < 48) {
      int tvs[4] = {tv4.x, tv4.y, tv4.z, tv4.w};
      int ups[4] = {up4.x, up4.y, up4.z, up4.w};
      int dns[4] = {dn4.x, dn4.y, dn4.z, dn4.w};
      int lfs[4] = {lf, tv4.x, tv4.y, tv4.z};
      int rts[4] = {tv4.y, tv4.z, tv4.w, rt};
      float a0[4] = {x0.x, x0.y, x0.z, x0.w};
      float a1[4] = {x1.x, x1.y, x1.z, x1.w};
      float a2[4] = {x2.x, x2.y, x2.z, x2.w};
      float a3[4] = {x3.x, x3.y, x3.z, x3.w};
      float4 fout;
      float* fo = (float*)&fout;
      unsigned pk4 = 0;
      #pragma unroll
      for (int k = 0; k < 4; ++k) {
        float xa = a0[k], xb = a1[k], xc = a2[k], xd = a3[k];
        int p = 0; float bst = xa;
        if (xb > bst) { bst = xb; p = 1; }
        if (xc > bst) { bst = xc; p = 2; }
        if (xd > bst) { bst = xd; p = 3; }
        int tv = tvs[k];
        float m = fmaxf(fmaxf(xa, xb), fmaxf(xc, xd));
        float e = expf(xa-m) + expf(xb-m) + expf(xc-m) + expf(xd-m);
        float xt = (tv==0) ? xa : (tv==1) ? xb : (tv==2) ? xc : xd;
        float logpt = xt - m - logf(e);
        float pt = expf(logpt);
        float om = 1.0f - pt;
        fo[k] = -(om*om)*logpt;
        pk4 |= (unsigned)(tv | (p << 4)) << (8*k);
        if (tv != 0) {
          lbits |= 1u << (tv-1);
          int col = lane*4 + k;
          bool interior = (row > 0) && (row < Hh-1) && (col > 0) && (col < Ww-1)
              && (ups[k]==tv) && (dns[k]==tv) && (lfs[k]==tv) && (rts[k]==tv);
          if (!interior) {
            if      (tv == 1) nib1 |= 1u << k;
            else if (tv == 2) nib2 |= 1u << k;
            else              nib3 |= 1u << k;
          }
        }
      }
      *(float4*)(focal + (size_t)slice*HW + idx) = fout;
      *(unsigned*)(tp + (size_t)slice*HW + idx) = pk4;
    }
    u64 m1 = (u64)nib1 << ((lane & 15)*4);
    u64 m2 = (u64)nib2 << ((lane & 15)*4);
    u64 m3 = (u64)nib3 << ((lane & 15)*4);
    #pragma unroll
    for (int off = 1; off < 16; off <<= 1) {
      m1 |= __shfl_xor(m1, off);
      m2 |= __shfl_xor(m2, off);
      m3 |= __shfl_xor(m3, off);
    }
    if (lane < 48 && (lane & 15) == 0) {
      int word = lane >> 4;
      size_t base = ((size_t)slice*3*Hh + row)*MROWSTRIDE + word;
      masks[base]                    = m1;
      masks[base + Hh*MROWSTRIDE]    = m2;
      masks[base + 2*Hh*MROWSTRIDE]  = m3;
    }
  }
  if (lbits) atomicOr(&sb, lbits);
  __syncthreads();
  if (threadIdx.x == 0) flags8[blockIdx.x] = sb;   // plain store, no init needed
}

// nearest set bit distance from column j in a 192-bit row mask; 1<<20 if empty
__device__ __forceinline__ int nearest_bit_dist(u64 m0, u64 m1, u64 m2, int j) {
  int dr = 1<<20, dl = 1<<20;
  u64 r0, r1, r2;
  if (j >= 128)      { r0 = 0;  r1 = 0;  r2 = m2 & (~0ull << (j-128)); }
  else if (j >= 64)  { r0 = 0;  r1 = m1 & (~0ull << (j-64)); r2 = m2; }
  else               { r0 = m0 & (~0ull << j); r1 = m1; r2 = m2; }
  if      (r0) dr = (__ffsll((unsigned long long)r0) - 1) - j;
  else if (r1) dr = (__ffsll((unsigned long long)r1) + 63) - j;
  else if (r2) dr = (__ffsll((unsigned long long)r2) + 127) - j;
  u64 l0, l1, l2;
  if (j < 64)        { l0 = (j==63) ? m0 : (m0 & ((1ull<<(j+1))-1)); l1 = 0; l2 = 0; }
  else if (j < 128)  { l0 = m0; l1 = (j==127) ? m1 : (m1 & ((1ull<<(j-63))-1)); l2 = 0; }
  else               { l0 = m0; l1 = m1; l2 = (j==191) ? m2 : (m2 & ((1ull<<(j-127))-1)); }
  if      (l2) dl = j - (191 - __clzll((long long)l2));
  else if (l1) dl = j - (127 - __clzll((long long)l1));
  else if (l0) dl = j - (63  - __clzll((long long)l0));
  return dl < dr ? dl : dr;
}

// exact nearest-seed distance: staged LDS rings for dr<=MARGIN, global beyond
__device__ __forceinline__ float edt_dist(const u64* __restrict__ smc,
    const u64* __restrict__ gmc, int li, int i, int j) {
  int best = 1 << 30;
  for (int dr = 0; dr <= MARGIN; ++dr) {
    if (dr*dr >= best) break;
    const u64* R = smc + (li-dr)*SSTRIDE;
    int dc = nearest_bit_dist(R[0], R[1], R[2], j);
    if (dc < (1<<20)) { int cand = dr*dr + dc*dc; if (cand < best) best = cand; }
    if (dr) {
      const u64* R2 = smc + (li+dr)*SSTRIDE;
      int dc2 = nearest_bit_dist(R2[0], R2[1], R2[2], j);
      if (dc2 < (1<<20)) { int cand = dr*dr + dc2*dc2; if (cand < best) best = cand; }
    }
  }
  for (int dr = MARGIN+1; dr < Hh; ++dr) {      // rare deep rings
    if (dr*dr >= best) break;
    int up = i - dr;
    if (up >= 0) {
      const u64* R = gmc + up*MROWSTRIDE;
      int dc = nearest_bit_dist(R[0], R[1], R[2], j);
      if (dc < (1<<20)) { int cand = dr*dr + dc*dc; if (cand < best) best = cand; }
    }
    int dn = i + dr;
    if (dn < Hh) {
      const u64* R = gmc + dn*MROWSTRIDE;
      int dc = nearest_bit_dist(R[0], R[1], R[2], j);
      if (dc < (1<<20)) { int cand = dr*dr + dc*dc; if (cand < best) best = cand; }
    }
  }
  return (best == (1 << 30)) ? 1.0e6f : sqrtf((float)best);
}

// wave-aggregated u16 list push
__device__ __forceinline__ void push16(unsigned short* list, unsigned* cnt,
    bool want, unsigned val) {
  u64 mask = __ballot(want);
  if (mask == 0) return;
  int lane = threadIdx.x & 63;
  int total = __popcll(mask);
  int leader = __ffsll((long long)mask) - 1;
  unsigned b = 0;
  if (lane == leader) b = atomicAdd(cnt, (unsigned)total);
  b = __shfl(b, leader);
  if (want) {
    int off = __popcll(mask & ((1ull << lane) - 1));
    list[b + off] = (unsigned short)val;
  }
}

// ---------------- Kernel B: tile-local exact EDT with LDS-staged masks -------
// grid: NSLICE*48 blocks of 256; block owns 4 rows (768 px) of one slice.
__global__ __launch_bounds__(256) void edt_kernel(const unsigned char* __restrict__ tp,
    const u64* __restrict__ masks, const unsigned int* __restrict__ flags8,
    float* __restrict__ wmap, float* __restrict__ mmn, float* __restrict__ mxx) {
  __shared__ u64 sm[3*SROWS*SSTRIDE];
  __shared__ __align__(16) float wacc[TPX];
  __shared__ unsigned short list[TPX];
  __shared__ unsigned cnt, sfl;
  __shared__ float smn[4], smx[4];
  int tile  = blockIdx.x % NTILE;
  int slice = blockIdx.x / NTILE;
  int r0 = tile*TROWS;
  int tid = threadIdx.x;

  if (tid == 0) {
    unsigned f = 0;
    #pragma unroll
    for (int p = 0; p < 8; ++p) f |= flags8[slice*8 + p];
    sfl = f; cnt = 0u;
  }
  __syncthreads();
  unsigned fl = sfl;
  bool empty = ((fl & 7u) == 0u);

  // stage masks: 3 classes x SROWS rows x 3 words
  for (int t = tid; t < 3*SROWS*3; t += 256) {
    int c = t / (SROWS*3);
    int rem = t - c*(SROWS*3);
    int sr = rem / 3, w = rem - sr*3;
    int gr = r0 - MARGIN + sr;
    sm[(c*SROWS + sr)*SSTRIDE + w] = (gr >= 0 && gr < Hh)
        ? masks[(((size_t)slice*3 + c)*Hh + gr)*MROWSTRIDE + w] : 0ull;
  }

  // phase 1: worklist build + wacc init (threads 0..191 = waves 0..2)
  if (tid < 192) {
    unsigned pk = *(const unsigned*)(tp + (size_t)slice*HW + r0*Ww + tid*4);
    #pragma unroll
    for (int k = 0; k < 4; ++k) {
      int px = tid*4 + k;
      int byte = (pk >> (8*k)) & 0xff;
      int tv = byte & 15, pv = byte >> 4;
      wacc[px] = (empty && pv != 0) ? 10.0f : 0.0f;
      bool diff = (tv != pv);
      int cA, cB;
      if (tv && pv) { cA = tv; cB = pv; } else { cA = tv | pv; cB = 0; }
      int rl = px / Ww, j = px - rl*Ww;
      push16(list, &cnt, diff,
             (unsigned)j | ((unsigned)rl << 8) | ((unsigned)cA << 10) | ((unsigned)cB << 12));
    }
  }
  __syncthreads();

  // phase 2: uniform searches over tile worklist (<=1 item/px -> plain update)
  unsigned n = cnt;
  const u64* gm0 = masks + (size_t)slice*3*Hh*MROWSTRIDE;
  for (unsigned kk = tid; kk < n; kk += 256) {
    unsigned item = list[kk];
    int j  = item & 255;
    int rl = (item >> 8) & 3;
    int cA = (item >> 10) & 3;
    int cB = (item >> 12) & 3;
    int i  = r0 + rl;
    int li = MARGIN + rl;
    float sum = 0.0f;
    if (cA && ((fl >> (cA-1)) & 1u))
      sum += edt_dist(sm + (cA-1)*SROWS*SSTRIDE, gm0 + (size_t)(cA-1)*Hh*MROWSTRIDE, li, i, j);
    if (cB && ((fl >> (cB-1)) & 1u))
      sum += edt_dist(sm + (cB-1)*SROWS*SSTRIDE, gm0 + (size_t)(cB-1)*Hh*MROWSTRIDE, li, i, j);
    wacc[rl*Ww + j] += sum;   // unique px per item
  }
  __syncthreads();

  // phase 3: dense writeback + per-tile min/max (plain stores, no init needed)
  float lmn = 1.0e30f, lmx = 0.0f;
  if (tid < 192) {
    float4 wv = *(const float4*)&wacc[tid*4];
    lmn = fminf(fminf(wv.x, wv.y), fminf(wv.z, wv.w));
    lmx = fmaxf(fmaxf(wv.x, wv.y), fmaxf(wv.z, wv.w));
    *(float4*)(wmap + (size_t)slice*HW + r0*Ww + tid*4) = wv;
  }
  for (int off = 32; off; off >>= 1) {
    lmn = fminf(lmn, __shfl_xor(lmn, off));
    lmx = fmaxf(lmx, __shfl_xor(lmx, off));
  }
  int wid = tid >> 6;
  if ((tid & 63) == 0) { smn[wid] = lmn; smx[wid] = lmx; }
  __syncthreads();
  if (tid == 0) {
    lmn = fminf(fminf(smn[0], smn[1]), fminf(smn[2], smn[3]));
    lmx = fmaxf(fmaxf(smx[0], smx[1]), fmaxf(smx[2], smx[3]));
    mmn[blockIdx.x] = lmn;
    mxx[blockIdx.x] = lmx;
  }
}

// ---------------- Kernel C: sum focal * exp(normalized wmap) -> partials -----
__global__ __launch_bounds__(256) void loss_kernel(const float* __restrict__ focal,
    const float* __restrict__ wmap, const float* __restrict__ mmn,
    const float* __restrict__ mxx, float* __restrict__ pp) {
  int part  = blockIdx.x % 9;
  int slice = blockIdx.x / 9;
  __shared__ float smm[2];
  if (threadIdx.x < 64) {
    float a = (threadIdx.x < NTILE) ? mmn[slice*NTILE + threadIdx.x] : 1.0e30f;
    float c = (threadIdx.x < NTILE) ? mxx[slice*NTILE + threadIdx.x] : 0.0f;
    for (int off = 32; off; off >>= 1) {
      a = fminf(a, __shfl_xor(a, off));
      c = fmaxf(c, __shfl_xor(c, off));
    }
    if (threadIdx.x == 0) { smm[0] = a; smm[1] = c; }
  }
  __syncthreads();
  float mn = smm[0], mx = smm[1];
  float inv = 1.0f/(mx - mn + 1e-6f);
  float acc = 0.0f;
  for (int it = 0; it < 4; ++it) {
    int idx = part*4096 + it*1024 + threadIdx.x*4;
    float4 f = *(const float4*)(focal + (size_t)slice*HW + idx);
    float4 w = *(const float4*)(wmap + (size_t)slice*HW + idx);
    acc += f.x * expf((w.x-mn)*inv);
    acc += f.y * expf((w.y-mn)*inv);
    acc += f.z * expf((w.z-mn)*inv);
    acc += f.w * expf((w.w-mn)*inv);
  }
  for (int off = 32; off; off >>= 1) acc += __shfl_xor(acc, off);
  __shared__ float sa[4];
  int wid = threadIdx.x >> 6;
  if ((threadIdx.x & 63) == 0) sa[wid] = acc;
  __syncthreads();
  if (threadIdx.x == 0) pp[blockIdx.x] = sa[0]+sa[1]+sa[2]+sa[3];
}

// ---------------- Kernel D: final reduce (plain store to d_out) --------------
__global__ __launch_bounds__(256) void final_kernel(const float* __restrict__ pp,
    float* __restrict__ out) {
  float acc = 0.0f;
  for (int i = threadIdx.x; i < NSLICE*9; i += 256) acc += pp[i];
  for (int off = 32; off; off >>= 1) acc += __shfl_xor(acc, off);
  __shared__ float sa[4];
  int wid = threadIdx.x >> 6;
  if ((threadIdx.x & 63) == 0) sa[wid] = acc;
  __syncthreads();
  if (threadIdx.x == 0) out[0] = sa[0]+sa[1]+sa[2]+sa[3];
}

extern "C" void kernel_launch(void* const* d_in, const int* in_sizes, int n_in,
                              void* d_out, int out_size, void* d_ws, size_t ws_size,
                              hipStream_t stream) {
  const float* inp = (const float*)d_in[0];
  const int*   tgt = (const int*)d_in[1];
  char* ws = (char*)d_ws;
  unsigned char* tp    = (unsigned char*)ws;                 // NVOX
  float*         focal = (float*)(ws + NVOX);                // 4*NVOX
  float*         wmap  = (float*)(ws + 5*NVOX);              // 4*NVOX
  u64*           masks = (u64*)(ws + 9*NVOX);                // MASKU64*8
  unsigned int*  flags8 = (unsigned int*)(ws + 9*NVOX + MASKU64*8); // NSLICE*8 u32
  float*         mmn   = (float*)(flags8 + NSLICE*8);        // NSLICE*48
  float*         mxx   = mmn + NSLICE*48;                    // NSLICE*48
  float*         pp    = mxx + NSLICE*48;                    // NSLICE*9

  // 4 nodes, zero memsets: every buffer is fully written before it is read.
  prep_kernel<<<NSLICE*8, 256, 0, stream>>>(inp, tgt, tp, focal, masks, flags8);
  edt_kernel<<<NSLICE*NTILE, 256, 0, stream>>>(tp, masks, flags8, wmap, mmn, mxx);
  loss_kernel<<<NSLICE*9, 256, 0, stream>>>(focal, wmap, mmn, mxx, pp);
  final_kernel<<<1, 256, 0, stream>>>(pp, (float*)d_out);
}